// Round 2
// baseline (1884.920 us; speedup 1.0000x reference)
//
#include <hip/hip_runtime.h>
#include <hip/hip_bf16.h>

// Problem dims
#define Bn 2
#define Tn 4
#define NCc 3
#define NKc 16
#define Hc 180
#define Wc 320
#define HWc (Hc * Wc)          // 57600
#define NPIX (Bn * HWc)        // 115200
#define CIN_LSTM 19            // NC + NK
#define GATES 64               // 4*NK
#define CIN_D 64               // T*NK

typedef __hip_bfloat16 bf16;

__device__ __forceinline__ float getv(const float* p, long i) { return p[i]; }
__device__ __forceinline__ float getv(const bf16* p, long i) { return __bfloat162float(p[i]); }
__device__ __forceinline__ void putv(float* p, long i, float v) { p[i] = v; }
__device__ __forceinline__ void putv(bf16* p, long i, float v) { p[i] = __float2bfloat16(v); }
__device__ __forceinline__ float sigm(float x) { return 1.0f / (1.0f + __expf(-x)); }
__device__ __forceinline__ float tanh_(float x) { return 1.0f - 2.0f / (__expf(2.0f * x) + 1.0f); }

// ---------------------------------------------------------------------------
// Dtype probe: reinterpret lstm_w (10944 elements) as bf16. Genuine bf16
// weights (scale 0.05) never exceed |v| ~ 0.3; float32 data misread as bf16
// yields mantissa-garbage halves with |v| > 64 or NaN with probability ~1.
// flag = 1 -> inputs are bf16; flag = 0 -> inputs are float32.
// ---------------------------------------------------------------------------
__global__ void __launch_bounds__(256) k_detect(const void* lstm_w_raw, int* flag)
{
    __shared__ int bad;
    if (threadIdx.x == 0) bad = 0;
    __syncthreads();
    const unsigned short* u = (const unsigned short*)lstm_w_raw;
    int local = 0;
    for (int i = threadIdx.x; i < GATES * CIN_LSTM * 9; i += 256) {
        unsigned int f32 = ((unsigned int)u[i]) << 16;
        float v = __uint_as_float(f32);
        if (!(fabsf(v) <= 64.0f)) local = 1;   // also catches NaN/Inf
    }
    if (local) atomicOr(&bad, 1);
    __syncthreads();
    if (threadIdx.x == 0) flag[0] = bad ? 0 : 1;
}

// ---------------------------------------------------------------------------
// ConvLSTM step t. h_t written into xcat channels [t*16, (t+1)*16);
// h_{t-1} read from xcat (zeros behavior via t==0 branch). c in-place.
// ---------------------------------------------------------------------------
template <typename T>
__device__ __forceinline__ void lstm_body(
    const T* __restrict__ X, const T* __restrict__ lstm_w, const T* __restrict__ lstm_b,
    const T* __restrict__ Wci, const T* __restrict__ Wcf, const T* __restrict__ Wco,
    float* __restrict__ c_buf, float* __restrict__ xcat, int t,
    float* sw, float* sb)
{
    for (int i = threadIdx.x; i < GATES * CIN_LSTM * 9; i += 256) {
        int co = i / (CIN_LSTM * 9);
        int tap = i - co * (CIN_LSTM * 9);
        sw[tap * GATES + co] = getv(lstm_w, i);
    }
    if (threadIdx.x < GATES) sb[threadIdx.x] = getv(lstm_b, threadIdx.x);
    __syncthreads();

    int idx = blockIdx.x * 256 + threadIdx.x;
    int b = idx / HWc;
    int p = idx - b * HWc;
    int y = p / Wc, x = p - (p / Wc) * Wc;

    float acc[GATES];
#pragma unroll
    for (int i = 0; i < GATES; i++) acc[i] = sb[i];

    const T* xt = X + (long)(b * Tn + t) * NCc * HWc;
    const float* hp = xcat + ((long)b * CIN_D + (t > 0 ? (t - 1) * NKc : 0)) * HWc;

#pragma unroll 1
    for (int cin = 0; cin < CIN_LSTM; cin++) {
#pragma unroll
        for (int ky = 0; ky < 3; ky++) {
            int yy = y + ky - 1;
            bool yok = (yy >= 0) && (yy < Hc);
#pragma unroll
            for (int kx = 0; kx < 3; kx++) {
                int xx = x + kx - 1;
                float v = 0.0f;
                if (yok && xx >= 0 && xx < Wc) {
                    if (cin < NCc)
                        v = getv(xt, (long)cin * HWc + yy * Wc + xx);
                    else if (t > 0)
                        v = hp[(long)(cin - NCc) * HWc + yy * Wc + xx];
                }
                const float* wp = &sw[((cin * 3 + ky) * 3 + kx) * GATES];
#pragma unroll
                for (int co = 0; co < GATES; co++) acc[co] += wp[co] * v;
            }
        }
    }

    float* cb = c_buf + (long)b * NKc * HWc + p;
    float* ho = xcat + ((long)b * CIN_D + t * NKc) * HWc + p;
#pragma unroll
    for (int kc = 0; kc < NKc; kc++) {
        float cprev = (t > 0) ? cb[(long)kc * HWc] : 0.0f;
        float wci = getv(Wci, (long)kc * HWc + p);
        float wcf = getv(Wcf, (long)kc * HWc + p);
        float wco = getv(Wco, (long)kc * HWc + p);
        float ig = acc[kc], fg = acc[NKc + kc], cg = acc[2 * NKc + kc], og = acc[3 * NKc + kc];
        float ii = sigm(ig + wci * cprev);
        float ff = sigm(fg + wcf * cprev);
        float cn = ff * cprev + ii * tanh_(cg);
        float oo = sigm(og + wco * cn);
        cb[(long)kc * HWc] = cn;
        ho[(long)kc * HWc] = oo * tanh_(cn);
    }
}

__global__ void __launch_bounds__(256) k_lstm_step(
    const void* X, const void* lstm_w, const void* lstm_b,
    const void* Wci, const void* Wcf, const void* Wco,
    const int* __restrict__ flag,
    float* c_buf, float* xcat, int t)
{
    __shared__ float sw[CIN_LSTM * 9 * GATES];  // 43.8 KB
    __shared__ float sb[GATES];
    if (flag[0])
        lstm_body<bf16>((const bf16*)X, (const bf16*)lstm_w, (const bf16*)lstm_b,
                        (const bf16*)Wci, (const bf16*)Wcf, (const bf16*)Wco,
                        c_buf, xcat, t, sw, sb);
    else
        lstm_body<float>((const float*)X, (const float*)lstm_w, (const float*)lstm_b,
                         (const float*)Wci, (const float*)Wcf, (const float*)Wco,
                         c_buf, xcat, t, sw, sb);
}

// ---------------------------------------------------------------------------
// Fused offset (18ch) + modulation (9ch, pre-activated 2*sigmoid) conv, 64->27.
// ---------------------------------------------------------------------------
template <typename T>
__device__ __forceinline__ void offmod_body(
    const float* __restrict__ xcat,
    const T* __restrict__ off_w, const T* __restrict__ off_b,
    const T* __restrict__ mod_w, const T* __restrict__ mod_b,
    float* __restrict__ offbuf, float* __restrict__ maskbuf,
    float* sw, float* sb)
{
    for (int i = threadIdx.x; i < 18 * CIN_D * 9; i += 256) {
        int o = i / (CIN_D * 9);
        int tap = i - o * (CIN_D * 9);
        sw[tap * 27 + o] = getv(off_w, i);
    }
    for (int i = threadIdx.x; i < 9 * CIN_D * 9; i += 256) {
        int o = i / (CIN_D * 9);
        int tap = i - o * (CIN_D * 9);
        sw[tap * 27 + 18 + o] = getv(mod_w, i);
    }
    if (threadIdx.x < 18) sb[threadIdx.x] = getv(off_b, threadIdx.x);
    else if (threadIdx.x < 27) sb[threadIdx.x] = getv(mod_b, threadIdx.x - 18);
    __syncthreads();

    int idx = blockIdx.x * 256 + threadIdx.x;
    int b = idx / HWc;
    int p = idx - b * HWc;
    int y = p / Wc, x = p - (p / Wc) * Wc;

    float acc[27];
#pragma unroll
    for (int i = 0; i < 27; i++) acc[i] = sb[i];

    const float* xb = xcat + (long)b * CIN_D * HWc;
#pragma unroll 1
    for (int cin = 0; cin < CIN_D; cin++) {
        const float* xc = xb + (long)cin * HWc;
#pragma unroll
        for (int ky = 0; ky < 3; ky++) {
            int yy = y + ky - 1;
            bool yok = (yy >= 0) && (yy < Hc);
#pragma unroll
            for (int kx = 0; kx < 3; kx++) {
                int xx = x + kx - 1;
                float v = (yok && xx >= 0 && xx < Wc) ? xc[yy * Wc + xx] : 0.0f;
                const float* wp = &sw[((cin * 3 + ky) * 3 + kx) * 27];
#pragma unroll
                for (int o = 0; o < 27; o++) acc[o] += wp[o] * v;
            }
        }
    }

#pragma unroll
    for (int o = 0; o < 18; o++)
        offbuf[((long)b * 18 + o) * HWc + p] = acc[o];
#pragma unroll
    for (int o = 0; o < 9; o++)
        maskbuf[((long)b * 9 + o) * HWc + p] = 2.0f * sigm(acc[18 + o]);
}

__global__ void __launch_bounds__(256) k_offmod(
    const float* xcat, const void* off_w, const void* off_b,
    const void* mod_w, const void* mod_b, const int* __restrict__ flag,
    float* offbuf, float* maskbuf)
{
    __shared__ float sw[CIN_D * 9 * 27];  // 62.2 KB
    __shared__ float sb[27];
    if (flag[0])
        offmod_body<bf16>(xcat, (const bf16*)off_w, (const bf16*)off_b,
                          (const bf16*)mod_w, (const bf16*)mod_b, offbuf, maskbuf, sw, sb);
    else
        offmod_body<float>(xcat, (const float*)off_w, (const float*)off_b,
                           (const float*)mod_w, (const float*)mod_b, offbuf, maskbuf, sw, sb);
}

// ---------------------------------------------------------------------------
// Deformable conv: bilinear sampling fused with einsum('bckhw,ock->bohw').
// ---------------------------------------------------------------------------
template <typename T>
__device__ __forceinline__ void deform_body(
    const float* __restrict__ xcat, const float* __restrict__ offbuf,
    const float* __restrict__ maskbuf,
    const T* __restrict__ def_w, const T* __restrict__ def_b,
    float* __restrict__ dcout, float* sw, float* sb)
{
    for (int i = threadIdx.x; i < NKc * CIN_D * 9; i += 256) {
        int co = i / (CIN_D * 9);
        int tap = i - co * (CIN_D * 9);
        sw[tap * NKc + co] = getv(def_w, i);
    }
    if (threadIdx.x < NKc) sb[threadIdx.x] = getv(def_b, threadIdx.x);
    __syncthreads();

    int idx = blockIdx.x * 256 + threadIdx.x;
    int b = idx / HWc;
    int p = idx - b * HWc;
    int y = p / Wc, x = p - (p / Wc) * Wc;

    float acc[NKc];
#pragma unroll
    for (int i = 0; i < NKc; i++) acc[i] = 0.0f;

    const float* xb = xcat + (long)b * CIN_D * HWc;

#pragma unroll 1
    for (int k = 0; k < 9; k++) {
        int ky = k / 3, kx = k - (k / 3) * 3;
        float dy = offbuf[((long)b * 18 + 2 * k) * HWc + p];
        float dx = offbuf[((long)b * 18 + 2 * k + 1) * HWc + p];
        float m = maskbuf[((long)b * 9 + k) * HWc + p];
        float py = (float)(y - 1 + ky) + dy;
        float px = (float)(x - 1 + kx) + dx;
        float y0f = floorf(py), x0f = floorf(px);
        int y0 = (int)y0f, x0 = (int)x0f;
        float wy1 = py - y0f, wx1 = px - x0f;
        float w00 = (1.0f - wy1) * (1.0f - wx1) * m;
        float w01 = (1.0f - wy1) * wx1 * m;
        float w10 = wy1 * (1.0f - wx1) * m;
        float w11 = wy1 * wx1 * m;
        bool vy0 = (y0 >= 0) && (y0 < Hc);
        bool vy1 = (y0 + 1 >= 0) && (y0 + 1 < Hc);
        bool vx0 = (x0 >= 0) && (x0 < Wc);
        bool vx1 = (x0 + 1 >= 0) && (x0 + 1 < Wc);
        if (!(vy0 && vx0)) w00 = 0.0f;
        if (!(vy0 && vx1)) w01 = 0.0f;
        if (!(vy1 && vx0)) w10 = 0.0f;
        if (!(vy1 && vx1)) w11 = 0.0f;
        int yc0 = min(max(y0, 0), Hc - 1);
        int yc1 = min(max(y0 + 1, 0), Hc - 1);
        int xc0 = min(max(x0, 0), Wc - 1);
        int xc1 = min(max(x0 + 1, 0), Wc - 1);
        int i00 = yc0 * Wc + xc0, i01 = yc0 * Wc + xc1;
        int i10 = yc1 * Wc + xc0, i11 = yc1 * Wc + xc1;

#pragma unroll 4
        for (int cin = 0; cin < CIN_D; cin++) {
            const float* xc = xb + (long)cin * HWc;
            float s = w00 * xc[i00] + w01 * xc[i01] + w10 * xc[i10] + w11 * xc[i11];
            const float* wrow = &sw[(cin * 9 + k) * NKc];
#pragma unroll
            for (int co = 0; co < NKc; co++) acc[co] += wrow[co] * s;
        }
    }

#pragma unroll
    for (int co = 0; co < NKc; co++)
        dcout[((long)b * NKc + co) * HWc + p] = acc[co] + sb[co];
}

__global__ void __launch_bounds__(256) k_deform(
    const float* xcat, const float* offbuf, const float* maskbuf,
    const void* def_w, const void* def_b, const int* __restrict__ flag,
    float* dcout)
{
    __shared__ float sw[CIN_D * 9 * NKc];  // 36.9 KB
    __shared__ float sb[NKc];
    if (flag[0])
        deform_body<bf16>(xcat, offbuf, maskbuf, (const bf16*)def_w, (const bf16*)def_b,
                          dcout, sw, sb);
    else
        deform_body<float>(xcat, offbuf, maskbuf, (const float*)def_w, (const float*)def_b,
                           dcout, sw, sb);
}

// ---------------------------------------------------------------------------
// Out conv (16 -> 48) + pixel_shuffle(4) + clip[0,255] + store (dtype per flag).
// ---------------------------------------------------------------------------
template <typename T>
__device__ __forceinline__ void outconv_body(
    const float* __restrict__ dcout, const T* __restrict__ out_w,
    const T* __restrict__ out_b, T* __restrict__ out, float* sw, float* sb)
{
    for (int i = threadIdx.x; i < 48 * NKc * 9; i += 256) {
        int co = i / (NKc * 9);
        int tap = i - co * (NKc * 9);
        sw[tap * 48 + co] = getv(out_w, i);
    }
    if (threadIdx.x < 48) sb[threadIdx.x] = getv(out_b, threadIdx.x);
    __syncthreads();

    int idx = blockIdx.x * 256 + threadIdx.x;
    int b = idx / HWc;
    int p = idx - b * HWc;
    int y = p / Wc, x = p - (p / Wc) * Wc;

    float acc[48];
#pragma unroll
    for (int i = 0; i < 48; i++) acc[i] = sb[i];

    const float* xb = dcout + (long)b * NKc * HWc;
#pragma unroll 1
    for (int cin = 0; cin < NKc; cin++) {
        const float* xc = xb + (long)cin * HWc;
#pragma unroll
        for (int ky = 0; ky < 3; ky++) {
            int yy = y + ky - 1;
            bool yok = (yy >= 0) && (yy < Hc);
#pragma unroll
            for (int kx = 0; kx < 3; kx++) {
                int xx = x + kx - 1;
                float v = (yok && xx >= 0 && xx < Wc) ? xc[yy * Wc + xx] : 0.0f;
                const float* wp = &sw[((cin * 3 + ky) * 3 + kx) * 48];
#pragma unroll
                for (int co = 0; co < 48; co++) acc[co] += wp[co] * v;
            }
        }
    }

#pragma unroll
    for (int co = 0; co < 48; co++) {
        int cc = co / 16;
        int r = co - cc * 16;
        int i = r / 4, j = r - (r / 4) * 4;
        float v = fminf(fmaxf(acc[co], 0.0f), 255.0f);
        long oi = (((long)b * 3 + cc) * (Hc * 4) + (y * 4 + i)) * (long)(Wc * 4) + (x * 4 + j);
        putv(out, oi, v);
    }
}

__global__ void __launch_bounds__(256) k_outconv(
    const float* dcout, const void* out_w, const void* out_b,
    const int* __restrict__ flag, void* out)
{
    __shared__ float sw[NKc * 9 * 48];  // 27.6 KB
    __shared__ float sb[48];
    if (flag[0])
        outconv_body<bf16>(dcout, (const bf16*)out_w, (const bf16*)out_b, (bf16*)out, sw, sb);
    else
        outconv_body<float>(dcout, (const float*)out_w, (const float*)out_b, (float*)out, sw, sb);
}

extern "C" void kernel_launch(void* const* d_in, const int* in_sizes, int n_in,
                              void* d_out, int out_size, void* d_ws, size_t ws_size,
                              hipStream_t stream) {
    const void* X      = d_in[0];
    const void* lstm_w = d_in[1];
    const void* lstm_b = d_in[2];
    const void* Wci    = d_in[3];
    const void* Wcf    = d_in[4];
    const void* Wco    = d_in[5];
    const void* off_w  = d_in[6];
    const void* off_b  = d_in[7];
    const void* mod_w  = d_in[8];
    const void* mod_b  = d_in[9];
    const void* def_w  = d_in[10];
    const void* def_b  = d_in[11];
    const void* out_w  = d_in[12];
    const void* out_b  = d_in[13];

    int* flag = (int*)d_ws;
    float* W = (float*)d_ws + 64;  // keep arrays 256B-aligned past the flag
    size_t o = 0;
    float* c_buf   = W + o; o += (size_t)Bn * NKc * HWc;
    float* xcat    = W + o; o += (size_t)Bn * CIN_D * HWc;
    float* offbuf  = W + o; o += (size_t)Bn * 18 * HWc;
    float* maskbuf = W + o; o += (size_t)Bn * 9 * HWc;
    float* dcout   = W + o; o += (size_t)Bn * NKc * HWc;

    dim3 grid(NPIX / 256);  // 450, exact
    dim3 blk(256);

    k_detect<<<1, blk, 0, stream>>>(lstm_w, flag);
    for (int t = 0; t < Tn; t++) {
        k_lstm_step<<<grid, blk, 0, stream>>>(X, lstm_w, lstm_b, Wci, Wcf, Wco,
                                              flag, c_buf, xcat, t);
    }
    k_offmod<<<grid, blk, 0, stream>>>(xcat, off_w, off_b, mod_w, mod_b, flag,
                                       offbuf, maskbuf);
    k_deform<<<grid, blk, 0, stream>>>(xcat, offbuf, maskbuf, def_w, def_b, flag, dcout);
    k_outconv<<<grid, blk, 0, stream>>>(dcout, out_w, out_b, flag, d_out);
}

// Round 3
// 850.891 us; speedup vs baseline: 2.2152x; 2.2152x over previous
//
#include <hip/hip_runtime.h>
#include <hip/hip_bf16.h>

// Problem dims
#define Bn 2
#define Tn 4
#define NCc 3
#define NKc 16
#define Hc 180
#define Wc 320
#define HWc (Hc * Wc)          // 57600
#define NPIX (Bn * HWc)        // 115200
#define CIN_LSTM 19            // NC + NK
#define GATES 64               // 4*NK
#define CIN_D 64               // T*NK
#define TAPS_L (CIN_LSTM * 9)  // 171

typedef __hip_bfloat16 bf16;

__device__ __forceinline__ float getv(const float* p, long i) { return p[i]; }
__device__ __forceinline__ float getv(const bf16* p, long i) {
    unsigned int u = ((unsigned int)((const unsigned short*)p)[i]) << 16;
    return __uint_as_float(u);
}
__device__ __forceinline__ void putv(float* p, long i, float v) { p[i] = v; }
__device__ __forceinline__ void putv(bf16* p, long i, float v) { p[i] = __float2bfloat16(v); }
__device__ __forceinline__ float sigm(float x) { return 1.0f / (1.0f + __expf(-x)); }
__device__ __forceinline__ float tanh_(float x) { return 1.0f - 2.0f / (__expf(2.0f * x) + 1.0f); }

// 4 consecutive values starting at row[x0] (alignment: x0 % 4 == 0)
__device__ __forceinline__ void load4(const float* row, int x0, float* d) {
    const float4 v = *(const float4*)(row + x0);
    d[0] = v.x; d[1] = v.y; d[2] = v.z; d[3] = v.w;
}
__device__ __forceinline__ void load4(const bf16* row, int x0, float* d) {
    ushort4 u = *(const ushort4*)((const unsigned short*)row + x0);
    d[0] = __uint_as_float(((unsigned int)u.x) << 16);
    d[1] = __uint_as_float(((unsigned int)u.y) << 16);
    d[2] = __uint_as_float(((unsigned int)u.z) << 16);
    d[3] = __uint_as_float(((unsigned int)u.w) << 16);
}

// ---------------------------------------------------------------------------
// Dtype probe (bf16 vs float32 inputs) -> flag in d_ws.
// ---------------------------------------------------------------------------
__global__ void __launch_bounds__(256) k_detect(const void* lstm_w_raw, int* flag)
{
    __shared__ int bad;
    if (threadIdx.x == 0) bad = 0;
    __syncthreads();
    const unsigned short* u = (const unsigned short*)lstm_w_raw;
    int local = 0;
    for (int i = threadIdx.x; i < GATES * TAPS_L; i += 256) {
        unsigned int f32 = ((unsigned int)u[i]) << 16;
        float v = __uint_as_float(f32);
        if (!(fabsf(v) <= 64.0f)) local = 1;   // catches NaN/Inf too
    }
    if (local) atomicOr(&bad, 1);
    __syncthreads();
    if (threadIdx.x == 0) flag[0] = bad ? 0 : 1;
}

// ---------------------------------------------------------------------------
// ConvLSTM step, v2.
// Block = 256 threads = 16 kc-groups x 16 lanes; each thread computes the
// 4 gates (i,f,c,o) of ONE kc for 4 adjacent pixels of one row segment
// (64 px per block; 320 = 5 segments/row). Weights in LDS laid out as
// [tap][kc][gate] so a thread's 4 weights are one ds_read_b128.
// acc = 16 VGPRs -> no spills. Elementwise LSTM fused. h_t -> xcat channels
// [t*16,(t+1)*16); c in-place; t==0 skips h planes (h==0) and c reads.
// ---------------------------------------------------------------------------
template <typename S>
__device__ __forceinline__ void conv_plane(
    const S* __restrict__ src, int cin, int y, int x0, int kc,
    const float* __restrict__ sw, float (&acc)[4][4])
{
#pragma unroll
    for (int ky = 0; ky < 3; ky++) {
        int yy = y + ky - 1;
        if (yy < 0 || yy >= Hc) continue;
        const S* row = src + (long)yy * Wc;
        float xs[6];
        xs[0] = (x0 > 0) ? getv(row, x0 - 1) : 0.0f;
        load4(row, x0, &xs[1]);
        xs[5] = (x0 + 4 < Wc) ? getv(row, x0 + 4) : 0.0f;
#pragma unroll
        for (int kx = 0; kx < 3; kx++) {
            int tap = (cin * 3 + ky) * 3 + kx;
            const float4 wq = *(const float4*)&sw[(tap * 16 + kc) * 4];
#pragma unroll
            for (int px = 0; px < 4; px++) {
                float v = xs[px + kx];
                acc[0][px] += wq.x * v;
                acc[1][px] += wq.y * v;
                acc[2][px] += wq.z * v;
                acc[3][px] += wq.w * v;
            }
        }
    }
}

template <typename T>
__device__ __forceinline__ void lstm2_body(
    const T* __restrict__ X, const T* __restrict__ lstm_w, const T* __restrict__ lstm_b,
    const T* __restrict__ Wci, const T* __restrict__ Wcf, const T* __restrict__ Wco,
    float* __restrict__ c_buf, float* __restrict__ xcat, int t,
    float* sw, float* sb)
{
    // weights: lstm_w[co][tap] -> sw[(tap*16 + kc)*4 + g], co = g*16 + kc
    for (int i = threadIdx.x; i < GATES * TAPS_L; i += 256) {
        int co = i / TAPS_L, tap = i - co * TAPS_L;
        int kc = co & 15, g = co >> 4;
        sw[(tap * 16 + kc) * 4 + g] = getv(lstm_w, i);
    }
    if (threadIdx.x < GATES) sb[threadIdx.x] = getv(lstm_b, threadIdx.x);
    __syncthreads();

    int blk = blockIdx.x;
    int seg = blk % 5; int rem = blk / 5;
    int y = rem % Hc; int b = rem / Hc;
    int kc = threadIdx.x >> 4, pl = threadIdx.x & 15;
    int x0 = seg * 64 + pl * 4;

    float acc[4][4];  // [gate][px]
#pragma unroll
    for (int px = 0; px < 4; px++) {
        acc[0][px] = sb[kc];
        acc[1][px] = sb[16 + kc];
        acc[2][px] = sb[32 + kc];
        acc[3][px] = sb[48 + kc];
    }

    const T* xt = X + (long)(b * Tn + t) * NCc * HWc;
#pragma unroll
    for (int cin = 0; cin < NCc; cin++)
        conv_plane(xt + (long)cin * HWc, cin, y, x0, kc, sw, acc);
    if (t > 0) {
        const float* hp = xcat + ((long)b * CIN_D + (t - 1) * NKc) * HWc;
#pragma unroll 1
        for (int cin = 0; cin < NKc; cin++)
            conv_plane(hp + (long)cin * HWc, cin + NCc, y, x0, kc, sw, acc);
    }

    long pbase = (long)y * Wc + x0;
    float* cb = c_buf + (long)(b * NKc + kc) * HWc + pbase;
    float cprev[4];
    if (t > 0) {
        const float4 cv = *(const float4*)cb;
        cprev[0] = cv.x; cprev[1] = cv.y; cprev[2] = cv.z; cprev[3] = cv.w;
    } else {
        cprev[0] = cprev[1] = cprev[2] = cprev[3] = 0.0f;
    }
    float wci[4], wcf[4], wco[4];
    load4(Wci + (long)kc * HWc + pbase, 0, wci);
    load4(Wcf + (long)kc * HWc + pbase, 0, wcf);
    load4(Wco + (long)kc * HWc + pbase, 0, wco);

    float cn4[4], h4[4];
#pragma unroll
    for (int px = 0; px < 4; px++) {
        float ii = sigm(acc[0][px] + wci[px] * cprev[px]);
        float ff = sigm(acc[1][px] + wcf[px] * cprev[px]);
        float cn = ff * cprev[px] + ii * tanh_(acc[2][px]);
        float oo = sigm(acc[3][px] + wco[px] * cn);
        cn4[px] = cn; h4[px] = oo * tanh_(cn);
    }
    *(float4*)cb = make_float4(cn4[0], cn4[1], cn4[2], cn4[3]);
    *(float4*)(xcat + ((long)b * CIN_D + t * NKc + kc) * HWc + pbase) =
        make_float4(h4[0], h4[1], h4[2], h4[3]);
}

__global__ void __launch_bounds__(256) k_lstm2(
    const void* X, const void* lstm_w, const void* lstm_b,
    const void* Wci, const void* Wcf, const void* Wco,
    const int* __restrict__ flag,
    float* c_buf, float* xcat, int t)
{
    __shared__ float sw[TAPS_L * GATES];  // 43.8 KB
    __shared__ float sb[GATES];
    if (flag[0])
        lstm2_body<bf16>((const bf16*)X, (const bf16*)lstm_w, (const bf16*)lstm_b,
                         (const bf16*)Wci, (const bf16*)Wcf, (const bf16*)Wco,
                         c_buf, xcat, t, sw, sb);
    else
        lstm2_body<float>((const float*)X, (const float*)lstm_w, (const float*)lstm_b,
                          (const float*)Wci, (const float*)Wcf, (const float*)Wco,
                          c_buf, xcat, t, sw, sb);
}

// ---------------------------------------------------------------------------
// Fused offset (18ch) + modulation (9ch, pre-activated 2*sigmoid) conv, 64->27.
// ---------------------------------------------------------------------------
template <typename T>
__device__ __forceinline__ void offmod_body(
    const float* __restrict__ xcat,
    const T* __restrict__ off_w, const T* __restrict__ off_b,
    const T* __restrict__ mod_w, const T* __restrict__ mod_b,
    float* __restrict__ offbuf, float* __restrict__ maskbuf,
    float* sw, float* sb)
{
    for (int i = threadIdx.x; i < 18 * CIN_D * 9; i += 256) {
        int o = i / (CIN_D * 9);
        int tap = i - o * (CIN_D * 9);
        sw[tap * 27 + o] = getv(off_w, i);
    }
    for (int i = threadIdx.x; i < 9 * CIN_D * 9; i += 256) {
        int o = i / (CIN_D * 9);
        int tap = i - o * (CIN_D * 9);
        sw[tap * 27 + 18 + o] = getv(mod_w, i);
    }
    if (threadIdx.x < 18) sb[threadIdx.x] = getv(off_b, threadIdx.x);
    else if (threadIdx.x < 27) sb[threadIdx.x] = getv(mod_b, threadIdx.x - 18);
    __syncthreads();

    int idx = blockIdx.x * 256 + threadIdx.x;
    int b = idx / HWc;
    int p = idx - b * HWc;
    int y = p / Wc, x = p - (p / Wc) * Wc;

    float acc[27];
#pragma unroll
    for (int i = 0; i < 27; i++) acc[i] = sb[i];

    const float* xb = xcat + (long)b * CIN_D * HWc;
#pragma unroll 1
    for (int cin = 0; cin < CIN_D; cin++) {
        const float* xc = xb + (long)cin * HWc;
#pragma unroll
        for (int ky = 0; ky < 3; ky++) {
            int yy = y + ky - 1;
            bool yok = (yy >= 0) && (yy < Hc);
#pragma unroll
            for (int kx = 0; kx < 3; kx++) {
                int xx = x + kx - 1;
                float v = (yok && xx >= 0 && xx < Wc) ? xc[yy * Wc + xx] : 0.0f;
                const float* wp = &sw[((cin * 3 + ky) * 3 + kx) * 27];
#pragma unroll
                for (int o = 0; o < 27; o++) acc[o] += wp[o] * v;
            }
        }
    }

#pragma unroll
    for (int o = 0; o < 18; o++)
        offbuf[((long)b * 18 + o) * HWc + p] = acc[o];
#pragma unroll
    for (int o = 0; o < 9; o++)
        maskbuf[((long)b * 9 + o) * HWc + p] = 2.0f * sigm(acc[18 + o]);
}

__global__ void __launch_bounds__(256) k_offmod(
    const float* xcat, const void* off_w, const void* off_b,
    const void* mod_w, const void* mod_b, const int* __restrict__ flag,
    float* offbuf, float* maskbuf)
{
    __shared__ float sw[CIN_D * 9 * 27];  // 62.2 KB
    __shared__ float sb[27];
    if (flag[0])
        offmod_body<bf16>(xcat, (const bf16*)off_w, (const bf16*)off_b,
                          (const bf16*)mod_w, (const bf16*)mod_b, offbuf, maskbuf, sw, sb);
    else
        offmod_body<float>(xcat, (const float*)off_w, (const float*)off_b,
                           (const float*)mod_w, (const float*)mod_b, offbuf, maskbuf, sw, sb);
}

// ---------------------------------------------------------------------------
// Deformable conv: bilinear sampling fused with einsum('bckhw,ock->bohw').
// ---------------------------------------------------------------------------
template <typename T>
__device__ __forceinline__ void deform_body(
    const float* __restrict__ xcat, const float* __restrict__ offbuf,
    const float* __restrict__ maskbuf,
    const T* __restrict__ def_w, const T* __restrict__ def_b,
    float* __restrict__ dcout, float* sw, float* sb)
{
    for (int i = threadIdx.x; i < NKc * CIN_D * 9; i += 256) {
        int co = i / (CIN_D * 9);
        int tap = i - co * (CIN_D * 9);
        sw[tap * NKc + co] = getv(def_w, i);
    }
    if (threadIdx.x < NKc) sb[threadIdx.x] = getv(def_b, threadIdx.x);
    __syncthreads();

    int idx = blockIdx.x * 256 + threadIdx.x;
    int b = idx / HWc;
    int p = idx - b * HWc;
    int y = p / Wc, x = p - (p / Wc) * Wc;

    float acc[NKc];
#pragma unroll
    for (int i = 0; i < NKc; i++) acc[i] = 0.0f;

    const float* xb = xcat + (long)b * CIN_D * HWc;

#pragma unroll 1
    for (int k = 0; k < 9; k++) {
        int ky = k / 3, kx = k - (k / 3) * 3;
        float dy = offbuf[((long)b * 18 + 2 * k) * HWc + p];
        float dx = offbuf[((long)b * 18 + 2 * k + 1) * HWc + p];
        float m = maskbuf[((long)b * 9 + k) * HWc + p];
        float py = (float)(y - 1 + ky) + dy;
        float px = (float)(x - 1 + kx) + dx;
        float y0f = floorf(py), x0f = floorf(px);
        int y0 = (int)y0f, x0 = (int)x0f;
        float wy1 = py - y0f, wx1 = px - x0f;
        float w00 = (1.0f - wy1) * (1.0f - wx1) * m;
        float w01 = (1.0f - wy1) * wx1 * m;
        float w10 = wy1 * (1.0f - wx1) * m;
        float w11 = wy1 * wx1 * m;
        bool vy0 = (y0 >= 0) && (y0 < Hc);
        bool vy1 = (y0 + 1 >= 0) && (y0 + 1 < Hc);
        bool vx0 = (x0 >= 0) && (x0 < Wc);
        bool vx1 = (x0 + 1 >= 0) && (x0 + 1 < Wc);
        if (!(vy0 && vx0)) w00 = 0.0f;
        if (!(vy0 && vx1)) w01 = 0.0f;
        if (!(vy1 && vx0)) w10 = 0.0f;
        if (!(vy1 && vx1)) w11 = 0.0f;
        int yc0 = min(max(y0, 0), Hc - 1);
        int yc1 = min(max(y0 + 1, 0), Hc - 1);
        int xc0 = min(max(x0, 0), Wc - 1);
        int xc1 = min(max(x0 + 1, 0), Wc - 1);
        int i00 = yc0 * Wc + xc0, i01 = yc0 * Wc + xc1;
        int i10 = yc1 * Wc + xc0, i11 = yc1 * Wc + xc1;

#pragma unroll 4
        for (int cin = 0; cin < CIN_D; cin++) {
            const float* xc = xb + (long)cin * HWc;
            float s = w00 * xc[i00] + w01 * xc[i01] + w10 * xc[i10] + w11 * xc[i11];
            const float* wrow = &sw[(cin * 9 + k) * NKc];
#pragma unroll
            for (int co = 0; co < NKc; co++) acc[co] += wrow[co] * s;
        }
    }

#pragma unroll
    for (int co = 0; co < NKc; co++)
        dcout[((long)b * NKc + co) * HWc + p] = acc[co] + sb[co];
}

__global__ void __launch_bounds__(256) k_deform(
    const float* xcat, const float* offbuf, const float* maskbuf,
    const void* def_w, const void* def_b, const int* __restrict__ flag,
    float* dcout)
{
    __shared__ float sw[CIN_D * 9 * NKc];  // 36.9 KB
    __shared__ float sb[NKc];
    if (flag[0])
        deform_body<bf16>(xcat, offbuf, maskbuf, (const bf16*)def_w, (const bf16*)def_b,
                          dcout, sw, sb);
    else
        deform_body<float>(xcat, offbuf, maskbuf, (const float*)def_w, (const float*)def_b,
                           dcout, sw, sb);
}

// ---------------------------------------------------------------------------
// Out conv (16 -> 48) + pixel_shuffle(4) + clip[0,255] + store (dtype per flag).
// ---------------------------------------------------------------------------
template <typename T>
__device__ __forceinline__ void outconv_body(
    const float* __restrict__ dcout, const T* __restrict__ out_w,
    const T* __restrict__ out_b, T* __restrict__ out, float* sw, float* sb)
{
    for (int i = threadIdx.x; i < 48 * NKc * 9; i += 256) {
        int co = i / (NKc * 9);
        int tap = i - co * (NKc * 9);
        sw[tap * 48 + co] = getv(out_w, i);
    }
    if (threadIdx.x < 48) sb[threadIdx.x] = getv(out_b, threadIdx.x);
    __syncthreads();

    int idx = blockIdx.x * 256 + threadIdx.x;
    int b = idx / HWc;
    int p = idx - b * HWc;
    int y = p / Wc, x = p - (p / Wc) * Wc;

    float acc[48];
#pragma unroll
    for (int i = 0; i < 48; i++) acc[i] = sb[i];

    const float* xb = dcout + (long)b * NKc * HWc;
#pragma unroll 1
    for (int cin = 0; cin < NKc; cin++) {
        const float* xc = xb + (long)cin * HWc;
#pragma unroll
        for (int ky = 0; ky < 3; ky++) {
            int yy = y + ky - 1;
            bool yok = (yy >= 0) && (yy < Hc);
#pragma unroll
            for (int kx = 0; kx < 3; kx++) {
                int xx = x + kx - 1;
                float v = (yok && xx >= 0 && xx < Wc) ? xc[yy * Wc + xx] : 0.0f;
                const float* wp = &sw[((cin * 3 + ky) * 3 + kx) * 48];
#pragma unroll
                for (int co = 0; co < 48; co++) acc[co] += wp[co] * v;
            }
        }
    }

#pragma unroll
    for (int co = 0; co < 48; co++) {
        int cc = co / 16;
        int r = co - cc * 16;
        int i = r / 4, j = r - (r / 4) * 4;
        float v = fminf(fmaxf(acc[co], 0.0f), 255.0f);
        long oi = (((long)b * 3 + cc) * (Hc * 4) + (y * 4 + i)) * (long)(Wc * 4) + (x * 4 + j);
        putv(out, oi, v);
    }
}

__global__ void __launch_bounds__(256) k_outconv(
    const float* dcout, const void* out_w, const void* out_b,
    const int* __restrict__ flag, void* out)
{
    __shared__ float sw[NKc * 9 * 48];  // 27.6 KB
    __shared__ float sb[48];
    if (flag[0])
        outconv_body<bf16>(dcout, (const bf16*)out_w, (const bf16*)out_b, (bf16*)out, sw, sb);
    else
        outconv_body<float>(dcout, (const float*)out_w, (const float*)out_b, (float*)out, sw, sb);
}

extern "C" void kernel_launch(void* const* d_in, const int* in_sizes, int n_in,
                              void* d_out, int out_size, void* d_ws, size_t ws_size,
                              hipStream_t stream) {
    const void* X      = d_in[0];
    const void* lstm_w = d_in[1];
    const void* lstm_b = d_in[2];
    const void* Wci    = d_in[3];
    const void* Wcf    = d_in[4];
    const void* Wco    = d_in[5];
    const void* off_w  = d_in[6];
    const void* off_b  = d_in[7];
    const void* mod_w  = d_in[8];
    const void* mod_b  = d_in[9];
    const void* def_w  = d_in[10];
    const void* def_b  = d_in[11];
    const void* out_w  = d_in[12];
    const void* out_b  = d_in[13];

    int* flag = (int*)d_ws;
    float* W = (float*)d_ws + 64;
    size_t o = 0;
    float* c_buf   = W + o; o += (size_t)Bn * NKc * HWc;
    float* xcat    = W + o; o += (size_t)Bn * CIN_D * HWc;
    float* offbuf  = W + o; o += (size_t)Bn * 18 * HWc;
    float* maskbuf = W + o; o += (size_t)Bn * 9 * HWc;
    float* dcout   = W + o; o += (size_t)Bn * NKc * HWc;

    dim3 blk(256);
    dim3 gridP(NPIX / 256);          // 450, exact
    dim3 gridL(Bn * Hc * 5);         // 1800 row-segment blocks

    k_detect<<<1, blk, 0, stream>>>(lstm_w, flag);
    for (int t = 0; t < Tn; t++) {
        k_lstm2<<<gridL, blk, 0, stream>>>(X, lstm_w, lstm_b, Wci, Wcf, Wco,
                                           flag, c_buf, xcat, t);
    }
    k_offmod<<<gridP, blk, 0, stream>>>(xcat, off_w, off_b, mod_w, mod_b, flag,
                                        offbuf, maskbuf);
    k_deform<<<gridP, blk, 0, stream>>>(xcat, offbuf, maskbuf, def_w, def_b, flag, dcout);
    k_outconv<<<gridP, blk, 0, stream>>>(dcout, out_w, out_b, flag, d_out);
}